// Round 14
// baseline (10357.527 us; speedup 1.0000x reference)
//
#include <hip/hip_runtime.h>
#include <hip/hip_fp16.h>
#include <math.h>

#define N_T 16384
#define S   128
#define S3  384
#define THREADS 256          // 4 waves, 1 per SIMD
#define L2E 1.4426950408889634f

typedef _Float16 half8 __attribute__((ext_vector_type(8)));
typedef float    f32x4 __attribute__((ext_vector_type(4)));

// native 2^x / 1/x where available; exact fallbacks keep compilation safe
#if __has_builtin(__builtin_amdgcn_exp2f)
#define EXP2(x) __builtin_amdgcn_exp2f(x)
#else
#define EXP2(x) exp2f(x)
#endif
#if __has_builtin(__builtin_amdgcn_rcpf)
#define RCP(x) __builtin_amdgcn_rcpf(x)
#else
#define RCP(x) (1.0f / (x))
#endif

// raw barrier: LDS-visibility only (NO vmcnt drain -> in-flight global loads
// can cross barriers freely, unlike __syncthreads()).
#define BAR() do { \
    asm volatile("s_waitcnt lgkmcnt(0)" ::: "memory"); \
    __builtin_amdgcn_s_barrier();                      \
    asm volatile("" ::: "memory");                     \
} while (0)

// ---------------------------------------------------------------------------
// Kernel 0: fold proj into w_ih (fp32). b_ih + r/z parts of b_hh folded;
// n-part of b_hh stays separate (scaled by r). gi columns carry the exp2
// prescale IN FP32: log2e (r,z rows), 2*log2e (n rows).
// ---------------------------------------------------------------------------
__global__ void prep_kernel(const float* __restrict__ w_ih,
                            const float* __restrict__ b_ih,
                            const float* __restrict__ b_hh,
                            const float* __restrict__ proj_w,
                            const float* __restrict__ proj_b,
                            float* __restrict__ Mt,
                            float* __restrict__ b2,
                            float* __restrict__ mc) {
    int j = blockIdx.x;    // 0..383
    int m = threadIdx.x;   // 0..127
    const float sc = (j < 2 * S) ? L2E : 2.f * L2E;
    float acc = 0.f;
    for (int k = 0; k < S - 1; ++k)
        acc += w_ih[j * S + k] * proj_w[k * S + m];
    Mt[m * S3 + j] = acc * sc;
    if (m == 0) {
        float a = 0.f;
        for (int k = 0; k < S - 1; ++k) a += w_ih[j * S + k] * proj_b[k];
        b2[j] = (b_ih[j] + ((j < 2 * S) ? b_hh[j] : 0.f) + a) * sc;
        mc[j] = w_ih[j * S + (S - 1)] * sc;
    }
}

// ---------------------------------------------------------------------------
// Kernel 0b: w_hh as packed f16 pairs, CONTIGUOUS pairing, UNSCALED (exact
// verified weight realization). Word i of row j = (w[j][2i], w[j][2i+1]) --
// serves both the dot2 fallback and the MFMA A-fragments.
// ---------------------------------------------------------------------------
__global__ void wcvt_kernel(const float* __restrict__ w_hh,
                            unsigned* __restrict__ Whh16) {
    int j = blockIdx.x;    // row 0..383
    int m = threadIdx.x;   // word 0..63
    __half2 p = __floats2half2_rn(w_hh[j * S + 2 * m], w_hh[j * S + 2 * m + 1]);
    Whh16[j * 64 + m] = *(unsigned*)&p;
}

// ---------------------------------------------------------------------------
// Kernel 1: gi[t][j] = b2[j] + dot(evs[t], M[j]) + (t==0 ? mc[j] : 0)  (fp32)
// ---------------------------------------------------------------------------
#define TB 32
__global__ void gi_kernel(const float* __restrict__ evs,
                          const float* __restrict__ Mt,
                          const float* __restrict__ b2,
                          const float* __restrict__ mc,
                          float* __restrict__ gi) {
    int j  = threadIdx.x;        // 0..383
    int t0 = blockIdx.x * TB;

    float mcol[S];
#pragma unroll
    for (int k = 0; k < S; ++k) mcol[k] = Mt[k * S3 + j];

    __shared__ float ev[TB][S];
    for (int i = j; i < TB * S; i += S3)
        ev[i / S][i % S] = evs[t0 * S + i];
    __syncthreads();

    float bb  = b2[j];
    float mcj = mc[j];
    for (int tt = 0; tt < TB; ++tt) {
        int t = t0 + tt;
        float acc = bb + ((t == 0) ? mcj : 0.f);
#pragma unroll
        for (int k = 0; k < S; ++k) acc += ev[tt][k] * mcol[k];
        gi[t * S3 + j] = acc;
    }
}

// ---------------------------------------------------------------------------
// Kernel 2: sequential GRU scan. 1 workgroup, 256 threads = 4 waves (1/SIMD).
//
// R14 = MFMA/VALU pipe overlap on the verified R13 structure. R13 counters:
// MFMA-pipe busy ~382cy/step (24 MFMA x ~16cy single-wave occupancy,
// issue-bound), VALU ~370cy, pipes NOT overlapped (source had all 24 MFMAs
// before any gate code). Change: phase the source by gate --
//   tiles{0,1} -> select a0 + r-sigmoid  (hides under tiles{2,3} issue)
//   tiles{2,3} -> select a1 + z-sigmoid  (hides under tiles{4,5} issue)
//   tiles{4,5} -> only n's short tail after the last MFMA.
// Identical ops, reordered source; builtins only (NOT the R8/R9/R11
// inline-asm miscompile class); no reassociation anywhere -> absmax 0.0
// expected. Same h16 double-buffer / 1 BAR per step / gi depth-4 pipeline.
// Self-test + verbatim R10 dot2 fallback retained.
// ---------------------------------------------------------------------------
#define DOT2(acc, wreg, hreg_) \
    asm("v_dot2_f32_f16 %0, %1, %2, %0" : "+v"(acc) : "v"(wreg), "v"(hreg_));

__global__ __attribute__((amdgpu_flat_work_group_size(THREADS, THREADS),
                          amdgpu_waves_per_eu(1, 1))) void
scan_kernel(const float* __restrict__ gi,
            const unsigned* __restrict__ Whh16,
            const float* __restrict__ h0,
            const float* __restrict__ b_hh,
            const float* __restrict__ final_w,
            const float* __restrict__ final_b,
            float* __restrict__ out) {
    const int tid = threadIdx.x;
    const int l   = tid & 63;
    const int c   = tid >> 6;           // wave 0..3

    __shared__ __align__(16) unsigned h16[2][64];   // (h[2i],h[2i+1]) pairs
    __shared__ float hfin[S];

    // ---- MFMA layout self-test (registers only; block-uniform verdict) ----
    // Assumed: A row = l&15, A k = 8*(l>>4)+i ; B k = 8*(l>>4)+i ;
    //          C col = l&15, C row = (l>>4)*4 + reg.
    bool usemfma;
    {
        const int g4 = l >> 4;
        half8 ta, tb;
#pragma unroll
        for (int i = 0; i < 8; ++i) {
            int k = 8 * g4 + i;
            ta[i] = (_Float16)(float)((l & 15) * 32 + k);
            tb[i] = (k == 5) ? (_Float16)1.f : (_Float16)0.f;
        }
        f32x4 tc = {0.f, 0.f, 0.f, 0.f};
        tc = __builtin_amdgcn_mfma_f32_16x16x32_f16(ta, tb, tc, 0, 0, 0);
        bool ok = true;
#pragma unroll
        for (int rg = 0; rg < 4; ++rg)
            ok = ok && (tc[rg] == (float)((4 * g4 + rg) * 32 + 5));
        usemfma = (bool)__all((int)ok);
    }

    if (usemfma) {
        // ================= MFMA path (phased) =================
        const int g4 = l >> 4;              // lane 16-group
        const int p  = l & 7;               // gate-row selector
        const int jj = 4 * g4 + (p & 3) + ((p & 4) ? 16 : 0);
        const int rr = (c << 5) + jj;       // owned gate row 0..127
        const bool writer = (l & 15) < 8;   // one writer per row
        const bool s0 = (p & 1) != 0, s1 = (p & 2) != 0, s2 = (p & 4) != 0;

        // A fragments: tile m = [r-lo,r-hi,z-lo,z-hi,n-lo,n-hi], K-chunk q.
        half8 a[6][4];
#pragma unroll
        for (int m = 0; m < 6; ++m) {
            const int j = 128 * (m >> 1) + 32 * c + 16 * (m & 1) + (l & 15);
            const unsigned* rowp = Whh16 + (size_t)j * 64 + 4 * g4;
#pragma unroll
            for (int q = 0; q < 4; ++q)
                a[m][q] = *(const half8*)(rowp + 16 * q);
        }

        float bn2  = b_hh[2 * S + rr] * (2.f * L2E);
        float hreg = h0[rr];
        if (writer)
            ((unsigned short*)&h16[0][0])[rr] =
                __half_as_ushort(__float2half(hreg));

        float gpr[4], gpz[4], gpn[4];
#pragma unroll
        for (int u = 0; u < 4; ++u) {
            gpr[u] = gi[(size_t)u * S3 + rr];
            gpz[u] = gi[(size_t)u * S3 + rr + S];
            gpn[u] = gi[(size_t)u * S3 + rr + 2 * S];
        }
        BAR();   // h16[0] visible

        for (int t = 0; t < N_T; t += 4) {
#pragma unroll
            for (int u = 0; u < 4; ++u) {
                const int tt = t + u;
                // broadcast-B fragments (uniform addr per 16-group), first
                const half8* hb = (const half8*)&h16[u & 1][0];
                half8 b[4];
#pragma unroll
                for (int q = 0; q < 4; ++q) b[q] = hb[4 * q + g4];

                // gi refill issued early (VMEM flies under the MFMA block)
                const float g_r = gpr[u], g_z = gpz[u], g_n = gpn[u];
                if (tt + 4 < N_T) {
                    gpr[u] = gi[(size_t)(tt + 4) * S3 + rr];
                    gpz[u] = gi[(size_t)(tt + 4) * S3 + rr + S];
                    gpn[u] = gi[(size_t)(tt + 4) * S3 + rr + 2 * S];
                }

                // ---- phase 1: r-gate tiles {0,1} ----
                f32x4 c0 = {0.f, 0.f, 0.f, 0.f}, c1 = c0;
#pragma unroll
                for (int q = 0; q < 4; ++q) {
                    c0 = __builtin_amdgcn_mfma_f32_16x16x32_f16(a[0][q], b[q], c0, 0, 0, 0);
                    c1 = __builtin_amdgcn_mfma_f32_16x16x32_f16(a[1][q], b[q], c1, 0, 0, 0);
                }
                f32x4 t0v = s2 ? c1 : c0;
                float a0 = s1 ? (s0 ? t0v.w : t0v.z) : (s0 ? t0v.y : t0v.x);
                float r  = RCP(1.f + EXP2(-__builtin_fmaf(L2E, a0, g_r)));

                // ---- phase 2: z-gate tiles {2,3} (r-chain hides here) ----
                f32x4 c2 = {0.f, 0.f, 0.f, 0.f}, c3 = c2;
#pragma unroll
                for (int q = 0; q < 4; ++q) {
                    c2 = __builtin_amdgcn_mfma_f32_16x16x32_f16(a[2][q], b[q], c2, 0, 0, 0);
                    c3 = __builtin_amdgcn_mfma_f32_16x16x32_f16(a[3][q], b[q], c3, 0, 0, 0);
                }
                f32x4 t1v = s2 ? c3 : c2;
                float a1 = s1 ? (s0 ? t1v.w : t1v.z) : (s0 ? t1v.y : t1v.x);
                float z  = RCP(1.f + EXP2(-__builtin_fmaf(L2E, a1, g_z)));

                // ---- phase 3: n-gate tiles {4,5} (z-chain hides here) ----
                f32x4 c4 = {0.f, 0.f, 0.f, 0.f}, c5 = c4;
#pragma unroll
                for (int q = 0; q < 4; ++q) {
                    c4 = __builtin_amdgcn_mfma_f32_16x16x32_f16(a[4][q], b[q], c4, 0, 0, 0);
                    c5 = __builtin_amdgcn_mfma_f32_16x16x32_f16(a[5][q], b[q], c5, 0, 0, 0);
                }
                f32x4 t2v = s2 ? c5 : c4;
                float a2 = s1 ? (s0 ? t2v.w : t2v.z) : (s0 ? t2v.y : t2v.x);
                float e  = EXP2(__builtin_fmaf(
                               r, __builtin_fmaf(2.f * L2E, a2, bn2), g_n));
                float n  = 1.f - 2.f * RCP(e + 1.f);   // tanh
                hreg = n + z * (hreg - n);

                if (writer)
                    ((unsigned short*)&h16[(u & 1) ^ 1][0])[rr] =
                        __half_as_ushort(__float2half(hreg));

                BAR();
            }
        }
        if (writer) hfin[rr] = hreg;
    } else {
        // ================= fallback: VERBATIM verified R10 loop =============
        const int lh  = l & 31;
        const int Rh  = (c << 5) + lh;
        const int kw0 = (l & 32);

        unsigned w0[32], w1[32], w2[32];
        {
            const unsigned* pw = Whh16 + (size_t)Rh * 64 + kw0;
#pragma unroll
            for (int i = 0; i < 32; ++i) {
                w0[i] = pw[i];
                w1[i] = pw[i + 128 * 64];
                w2[i] = pw[i + 256 * 64];
            }
        }

        float bn2  = b_hh[2 * S + Rh] * (2.f * L2E);
        float hreg = h0[Rh];
        if (l < 32)
            ((unsigned short*)&h16[0][0])[Rh] =
                __half_as_ushort(__float2half(hreg));

        float gpr[4], gpz[4], gpn[4];
#pragma unroll
        for (int u = 0; u < 4; ++u) {
            gpr[u] = gi[(size_t)u * S3 + Rh];
            gpz[u] = gi[(size_t)u * S3 + Rh + S];
            gpn[u] = gi[(size_t)u * S3 + Rh + 2 * S];
        }
        BAR();

        for (int t = 0; t < N_T; t += 4) {
#pragma unroll
            for (int u = 0; u < 4; ++u) {
                const int tt = t + u;
                const uint4* hp = (const uint4*)&h16[u & 1][kw0];
                uint4 q[8];
#pragma unroll
                for (int i = 0; i < 8; ++i) q[i] = hp[i];

                float a0 = 0.f, a1 = 0.f, a2 = 0.f;
#pragma unroll
                for (int i = 0; i < 8; ++i) {
                    const unsigned hw[4] = { q[i].x, q[i].y, q[i].z, q[i].w };
#pragma unroll
                    for (int jj2 = 0; jj2 < 4; ++jj2) {
                        const int idx = 4 * i + jj2;
                        DOT2(a0, w0[idx], hw[jj2])
                        DOT2(a1, w1[idx], hw[jj2])
                        DOT2(a2, w2[idx], hw[jj2])
                    }
                }
                a0 += __shfl_xor(a0, 32, 64);
                a1 += __shfl_xor(a1, 32, 64);
                a2 += __shfl_xor(a2, 32, 64);

                float r  = RCP(1.f + EXP2(-__builtin_fmaf(L2E, a0, gpr[u])));
                float z  = RCP(1.f + EXP2(-__builtin_fmaf(L2E, a1, gpz[u])));
                float e  = EXP2(__builtin_fmaf(
                               r, __builtin_fmaf(2.f * L2E, a2, bn2), gpn[u]));
                float n  = 1.f - 2.f * RCP(e + 1.f);
                hreg = n + z * (hreg - n);

                if (l < 32)
                    ((unsigned short*)&h16[(u & 1) ^ 1][0])[Rh] =
                        __half_as_ushort(__float2half(hreg));

                if (tt + 4 < N_T) {
                    gpr[u] = gi[(size_t)(tt + 4) * S3 + Rh];
                    gpz[u] = gi[(size_t)(tt + 4) * S3 + Rh + S];
                    gpn[u] = gi[(size_t)(tt + 4) * S3 + Rh + 2 * S];
                }

                BAR();
            }
        }
        if (l < 32) hfin[Rh] = hreg;
    }

    // common epilogue: out = h @ final_w.T + final_b
    BAR();
    if (tid < 3) {
        float acc = final_b[tid];
        for (int k = 0; k < S; ++k) acc += final_w[tid * S + k] * hfin[k];
        out[tid] = acc;
    }
}

// ---------------------------------------------------------------------------
extern "C" void kernel_launch(void* const* d_in, const int* in_sizes, int n_in,
                              void* d_out, int out_size, void* d_ws, size_t ws_size,
                              hipStream_t stream) {
    const float* evs     = (const float*)d_in[0];
    const float* h0      = (const float*)d_in[1];
    const float* w_ih    = (const float*)d_in[2];
    const float* w_hh    = (const float*)d_in[3];
    const float* b_ih    = (const float*)d_in[4];
    const float* b_hh    = (const float*)d_in[5];
    const float* proj_w  = (const float*)d_in[6];
    const float* proj_b  = (const float*)d_in[7];
    const float* final_w = (const float*)d_in[8];
    const float* final_b = (const float*)d_in[9];
    float* out = (float*)d_out;

    // workspace layout (floats)
    float* gi = (float*)d_ws;                  // N_T * 384
    float* Mt = gi + (size_t)N_T * S3;         // 128 * 384
    float* b2 = Mt + (size_t)S * S3;           // 384
    float* mc = b2 + S3;                       // 384
    unsigned* Whh16 = (unsigned*)(mc + S3);    // 384 * 64 packed f16 pairs

    prep_kernel<<<S3, S, 0, stream>>>(w_ih, b_ih, b_hh, proj_w, proj_b, Mt, b2, mc);
    wcvt_kernel<<<S3, 64, 0, stream>>>(w_hh, Whh16);
    gi_kernel<<<N_T / TB, S3, 0, stream>>>(evs, Mt, b2, mc, gi);
    scan_kernel<<<1, THREADS, 0, stream>>>(gi, Whh16, h0, b_hh,
                                           final_w, final_b, out);
}